// Round 9
// baseline (552.130 us; speedup 1.0000x reference)
//
#include <hip/hip_runtime.h>
#include <math.h>

#define Bn 128
#define Sn 200
#define NC3n 4000
#define REPS 2

__device__ __forceinline__ float sigmf(float x) { return 1.f / (1.f + __expf(-x)); }
__device__ __forceinline__ float rlane(float v, int k) {
    return __int_as_float(__builtin_amdgcn_readlane(__float_as_int(v), k));
}

#define UPD(q, cbase) { int d = cc - (cbase); if ((unsigned)d < 4u) { \
    q.x = (d==0)?v:q.x; q.y = (d==1)?v:q.y; q.z = (d==2)?v:q.z; q.w = (d==3)?v:q.w; } }

// ============ GRU + mlp1 + alpha (recurrence run REPS times, idempotent) ============
__global__ __launch_bounds__(256, 2) void gru2x_kernel(
    const int* __restrict__ d_seq, const int* __restrict__ r_seq,
    const float* __restrict__ D_w, const float* __restrict__ v_d,
    const float* __restrict__ R_w, const float* __restrict__ W_ih,
    const float* __restrict__ W_hh, const float* __restrict__ b_ih,
    const float* __restrict__ b_hh,
    const float* __restrict__ l1_w1, const float* __restrict__ l1_b1,
    const float* __restrict__ l1_w2, const float* __restrict__ l1_b2,
    float* __restrict__ out_alpha, float* __restrict__ out_h)
{
    __shared__ __align__(16) float ring[2][16][64];
    __shared__ __align__(16) float pPart[Sn][4];
    __shared__ float u_l[192], w0_l[192], w1_l[192];
    __shared__ float hg[2][192];
    __shared__ float gam_l[Sn];
    __shared__ int   r_l[Sn];

    const int tid = threadIdx.x;
    const int b   = blockIdx.x;
    const int wid = tid >> 6;
    const int j   = tid & 63;

    if (tid < Sn) {
        gam_l[tid] = D_w[d_seq[b * Sn + tid]];
        r_l[tid]   = r_seq[b * Sn + tid];
    }
    if (tid < 192) {
        const float4* rp  = (const float4*)(W_ih + (size_t)tid * 128);
        const float4* vd4 = (const float4*)v_d;
        const float4* q04 = (const float4*)R_w;
        const float4* q14 = (const float4*)(R_w + 64);
        float u = 0.f, w0 = 0.f, w1 = 0.f;
        #pragma unroll 4
        for (int k = 0; k < 16; ++k) {
            float4 a  = rp[k];
            float4 bb = rp[16 + k];
            float4 vd = vd4[k], q0 = q04[k], q1 = q14[k];
            u  += a.x*vd.x + a.y*vd.y + a.z*vd.z + a.w*vd.w;
            w0 += bb.x*q0.x + bb.y*q0.y + bb.z*q0.z + bb.w*q0.w;
            w1 += bb.x*q1.x + bb.y*q1.y + bb.z*q1.z + bb.w*q1.w;
        }
        float bih = b_ih[tid];
        u_l[tid]  = u;
        w0_l[tid] = w0 + bih;
        w1_l[tid] = w1 + bih;
    }
    float w[64];
    {
        const float* src = (wid < 3) ? (W_hh + (size_t)(wid * 64 + j) * 64)
                                     : (l1_w1 + (size_t)j * 64);
        const float4* s4 = (const float4*)src;
        #pragma unroll
        for (int k = 0; k < 16; ++k) {
            float4 v = s4[k];
            w[4*k+0]=v.x; w[4*k+1]=v.y; w[4*k+2]=v.z; w[4*k+3]=v.w;
        }
    }
    float bown = 0.f, l1b = 0.f, l1w2v = 0.f;
    if (wid < 3) bown = b_hh[wid * 64 + j];
    else { l1b = l1_b1[j]; l1w2v = l1_w2[j]; }
    const float l1b2c = l1_b2[0];
    __syncthreads();

    const float uj  = u_l[j],  u1  = u_l[64+j],  u2  = u_l[128+j];
    const float w00 = w0_l[j], w01 = w0_l[64+j], w02 = w0_l[128+j];
    const float w10 = w1_l[j], w11 = w1_l[64+j], w12 = w1_l[128+j];

    float* outh_base = out_h + (size_t)b * Sn * 64;
    const int rloc = 4 * wid + (j >> 4);
    const int cloc = (j & 15) * 4;

    for (int rep = 0; rep < REPS; ++rep) {
        asm volatile("" ::: "memory");
        if (wid < 3) hg[0][wid * 64 + j] = bown;   // h0 = 0 -> hg(t=0) = b_hh
        __syncthreads();
        float vh = 0.f;
        for (int t = 0; t < Sn; ++t) {
            if (t && (t & 15) == 0) {              // flush completed ring half
                const int hb = ((t >> 4) & 1) ^ 1;
                float4 v4 = *(const float4*)&ring[hb][rloc][cloc];
                *(float4*)(outh_base + (size_t)(t - 16 + rloc) * 64 + cloc) = v4;
            }
            const int buf = t & 1;
            float gam = gam_l[t];
            int   r   = r_l[t];
            float hr = hg[buf][j], hz = hg[buf][64+j], hn = hg[buf][128+j];
            float rg = sigmf(fmaf(gam, uj, r ? w10 : w00) + hr);
            float zg = sigmf(fmaf(gam, u1, r ? w11 : w01) + hz);
            float e2 = __expf(2.f * (fmaf(gam, u2, r ? w12 : w02) + rg * hn));
            float ng = (e2 - 1.f) / (e2 + 1.f);    // tanh
            vh = (1.f - zg) * ng + zg * vh;
            float a0=0.f, a1=0.f, a2=0.f, a3=0.f;
            #pragma unroll
            for (int k = 0; k < 64; k += 4) {
                a0 = fmaf(w[k+0], rlane(vh, k+0), a0);
                a1 = fmaf(w[k+1], rlane(vh, k+1), a1);
                a2 = fmaf(w[k+2], rlane(vh, k+2), a2);
                a3 = fmaf(w[k+3], rlane(vh, k+3), a3);
            }
            float dot = (a0 + a1) + (a2 + a3);
            if (wid < 3) {
                hg[buf ^ 1][wid * 64 + j] = bown + dot;
            } else {
                float p = fmaxf(dot + l1b, 0.f) * l1w2v;
                p += __shfl_xor(p, 1);
                p += __shfl_xor(p, 2);
                p += __shfl_xor(p, 4);
                p += __shfl_xor(p, 8);
                if ((j & 15) == 0) pPart[t][j >> 4] = p;
                ring[(t >> 4) & 1][t & 15][j] = vh;
            }
            __syncthreads();
        }
        if (wid < 2) {                             // rows 192..199
            float4 v4 = *(const float4*)&ring[0][rloc][cloc];
            *(float4*)(outh_base + (size_t)(192 + rloc) * 64 + cloc) = v4;
        }
        if (tid == 0) {
            float alpha = 0.f;
            for (int t = 0; t < Sn; ++t) {
                float4 pp = *(const float4*)&pPart[t][0];
                float an = ((pp.x + pp.y) + (pp.z + pp.w)) + l1b2c;
                float gam = gam_l[t];
                int   r   = r_l[t];
                bool cond = (alpha - gam) >= 0.f;
                alpha = r ? (cond ? an : alpha) : (cond ? alpha : an);
                out_alpha[b * Sn + t] = alpha;
            }
        }
        __syncthreads();
    }
}

// ============ C3 chain + forward-fill (stream section run REPS times) ============
__global__ __launch_bounds__(256) void fill2x_kernel(
    const int* __restrict__ c3_seq, const int* __restrict__ d_seq,
    const int* __restrict__ r_seq, const float* __restrict__ v_c3,
    const float* __restrict__ D_w, const float* __restrict__ v_d,
    const float* __restrict__ R_w,
    const float* __restrict__ l2_w1, const float* __restrict__ l2_b1,
    const float* __restrict__ l2_w2, const float* __restrict__ l2_b2,
    float* __restrict__ out_c3)
{
    __shared__ float gam_l[Sn]; __shared__ float val_l[Sn];
    __shared__ int   r_l[Sn];   __shared__ int c3_l[Sn];
    __shared__ int   succ_l[Sn]; __shared__ int root_l[Sn];
    __shared__ float A_l[64], B_l[64], C0_l[64], C1_l[64], W2_l[64];
    __shared__ float l2b2_sh;

    const int tid = threadIdx.x;
    const int fb  = blockIdx.x;
    const int b   = fb >> 2;
    const int qt  = fb & 3;

    if (tid < Sn) {
        gam_l[tid] = D_w[d_seq[b*Sn + tid]];
        r_l[tid]   = r_seq[b*Sn + tid];
        c3_l[tid]  = c3_seq[b*Sn + tid];
    }
    if (tid < 64) {
        const float4* row4 = (const float4*)(l2_w1 + (size_t)tid * 192);
        const float4* vc4  = (const float4*)v_c3;
        const float4* vd4  = (const float4*)v_d;
        const float4* q04  = (const float4*)R_w;
        const float4* q14  = (const float4*)(R_w + 64);
        float a2=0.f, b2=0.f, c0=0.f, c1=0.f;
        #pragma unroll 4
        for (int k = 0; k < 16; ++k) {
            float4 ra = row4[k], rb = row4[16+k], rc = row4[32+k];
            float4 vc = vc4[k], vd = vd4[k], q0 = q04[k], q1 = q14[k];
            a2 += ra.x*vc.x + ra.y*vc.y + ra.z*vc.z + ra.w*vc.w;
            b2 += rb.x*vd.x + rb.y*vd.y + rb.z*vd.z + rb.w*vd.w;
            c0 += rc.x*q0.x + rc.y*q0.y + rc.z*q0.z + rc.w*q0.w;
            c1 += rc.x*q1.x + rc.y*q1.y + rc.z*q1.z + rc.w*q1.w;
        }
        A_l[tid]  = a2;
        B_l[tid]  = b2;
        C0_l[tid] = c0 + l2_b1[tid];
        C1_l[tid] = c1 + l2_b1[tid];
        W2_l[tid] = l2_w2[tid];
    }
    if (tid == 0) l2b2_sh = l2_b2[0];
    __syncthreads();
    if (tid < Sn) {
        int c = c3_l[tid];
        int s = -1;
        for (int u = tid + 1; u < Sn; ++u)
            if (c3_l[u] == c) { s = u; break; }
        succ_l[tid] = s;
        int rt = 1;
        for (int u = 0; u < tid; ++u)
            if (c3_l[u] == c) { rt = 0; break; }
        root_l[tid] = rt;
    }
    __syncthreads();
    {   // chain walk, 16-lane groups
        const int g  = tid >> 4;
        const int l  = tid & 15;
        const int j0 = l * 4;
        float A0=A_l[j0],  A1=A_l[j0+1],  A2=A_l[j0+2],  A3=A_l[j0+3];
        float B0=B_l[j0],  B1=B_l[j0+1],  B2=B_l[j0+2],  B3=B_l[j0+3];
        float C00=C0_l[j0],C01=C0_l[j0+1],C02=C0_l[j0+2],C03=C0_l[j0+3];
        float C10=C1_l[j0],C11=C1_l[j0+1],C12=C1_l[j0+2],C13=C1_l[j0+3];
        float W0=W2_l[j0], W1=W2_l[j0+1], W2v=W2_l[j0+2],W3=W2_l[j0+3];
        float l2b2 = l2b2_sh;
        for (int t0 = g; t0 < Sn; t0 += 16) {
            if (!root_l[t0]) continue;
            float beta = 0.f;
            int t = t0;
            while (t >= 0) {
                float gam = gam_l[t];
                int   r   = r_l[t];
                float s = W0*fmaxf(A0*beta + B0*gam + (r ? C10 : C00), 0.f)
                        + W1*fmaxf(A1*beta + B1*gam + (r ? C11 : C01), 0.f)
                        + W2v*fmaxf(A2*beta + B2*gam + (r ? C12 : C02), 0.f)
                        + W3*fmaxf(A3*beta + B3*gam + (r ? C13 : C03), 0.f);
                s += __shfl_xor(s, 1, 16);
                s += __shfl_xor(s, 2, 16);
                s += __shfl_xor(s, 4, 16);
                s += __shfl_xor(s, 8, 16);
                beta = s + l2b2;
                if (l == 0) val_l[t] = beta;
                t = succ_l[t];
            }
        }
    }
    __syncthreads();
    // streaming section, run REPS times (idempotent)
    const int cA = tid*4, cB = 1024 + tid*4, cC = 2048 + tid*4, cD = 3072 + tid*4;
    const int t0 = qt * 50;
    const bool doD = (tid < 232);
    for (int rep = 0; rep < REPS; ++rep) {
        asm volatile("" ::: "memory");
        float4 qA = make_float4(0.f,0.f,0.f,0.f), qB = qA, qC = qA, qD = qA;
        for (int t = 0; t < t0; ++t) {            // pre-scan (no stores)
            int cc = c3_l[t]; float v = val_l[t];
            UPD(qA, cA) UPD(qB, cB) UPD(qC, cC) UPD(qD, cD)
        }
        float* rowp = out_c3 + (size_t)b * Sn * NC3n + (size_t)t0 * NC3n;
        for (int t = t0; t < t0 + 50; ++t) {
            int cc = c3_l[t]; float v = val_l[t];
            UPD(qA, cA) UPD(qB, cB) UPD(qC, cC) UPD(qD, cD)
            *(float4*)(rowp + cA) = qA;
            *(float4*)(rowp + cB) = qB;
            *(float4*)(rowp + cC) = qC;
            if (doD) *(float4*)(rowp + cD) = qD;
            rowp += NC3n;
        }
    }
}

extern "C" void kernel_launch(void* const* d_in, const int* in_sizes, int n_in,
                              void* d_out, int out_size, void* d_ws, size_t ws_size,
                              hipStream_t stream)
{
    const int*   c3_seq = (const int*)  d_in[0];
    const int*   d_seq  = (const int*)  d_in[1];
    const int*   r_seq  = (const int*)  d_in[2];
    const float* v_c3   = (const float*)d_in[3];
    const float* D_w    = (const float*)d_in[4];
    const float* v_d    = (const float*)d_in[5];
    const float* R_w    = (const float*)d_in[6];
    const float* W_ih   = (const float*)d_in[7];
    const float* W_hh   = (const float*)d_in[8];
    const float* b_ih   = (const float*)d_in[9];
    const float* b_hh   = (const float*)d_in[10];
    const float* l1_w1  = (const float*)d_in[11];
    const float* l1_b1  = (const float*)d_in[12];
    const float* l1_w2  = (const float*)d_in[13];
    const float* l1_b2  = (const float*)d_in[14];
    const float* l2_w1  = (const float*)d_in[15];
    const float* l2_b1  = (const float*)d_in[16];
    const float* l2_w2  = (const float*)d_in[17];
    const float* l2_b2  = (const float*)d_in[18];

    float* out_alpha = (float*)d_out;
    float* out_h     = out_alpha + Bn*Sn;
    float* out_c3    = out_h + (size_t)Bn*Sn*64;

    gru2x_kernel<<<Bn, 256, 0, stream>>>(
        d_seq, r_seq, D_w, v_d, R_w, W_ih, W_hh, b_ih, b_hh,
        l1_w1, l1_b1, l1_w2, l1_b2, out_alpha, out_h);
    fill2x_kernel<<<Bn * 4, 256, 0, stream>>>(
        c3_seq, d_seq, r_seq, v_c3, D_w, v_d, R_w,
        l2_w1, l2_b1, l2_w2, l2_b2, out_c3);
}

// Round 10
// 205.777 us; speedup vs baseline: 2.6831x; 2.6831x over previous
//
#include <hip/hip_runtime.h>
#include <math.h>

#define Bn 128
#define Sn 200
#define NC3n 4000
#define GRUB 64                 // 64 blocks x 2 rows = 128 GRU rows
#define FILLB 256               // (b, t-half): 256 fill blocks

__device__ __forceinline__ float sigmf(float x) { return 1.f / (1.f + __expf(-x)); }
__device__ __forceinline__ float rlanef(float v, int k) {
    return __int_as_float(__builtin_amdgcn_readlane(__float_as_int(v), k));
}

#define UPD(q, cbase) { int d = cc - (cbase); if ((unsigned)d < 4u) { \
    q.x = (d==0)?v:q.x; q.y = (d==1)?v:q.y; q.z = (d==2)?v:q.z; q.w = (d==3)?v:q.w; } }

struct GruLds {                 // ~33.4 KB
    float ring[2][2][16][64];   // [rw][half][slot][j] out_h staging
    float pPart[2][Sn][4];      // mlp1 16-lane partials
    float hbc[8][64];           // per-wave h broadcast strips
    float u[192], w0[192], w1[192];
    float hg[2][2][192];        // [rw][buf] W_hh@h + b_hh ping-pong
    float gam[2][Sn];
    int   r[2][Sn];
};
struct FillLds {                // ~6.2 KB
    float gam[Sn], val[Sn];
    int   r[Sn], c3[Sn], succ[Sn], root[Sn];
    float A[64], Bv[64], C0[64], C1[64], W2[64];
    float l2b2;
};

__global__ __launch_bounds__(512, 2) void fused3_kernel(
    const int* __restrict__ c3_seq, const int* __restrict__ d_seq,
    const int* __restrict__ r_seq, const float* __restrict__ v_c3,
    const float* __restrict__ D_w, const float* __restrict__ v_d,
    const float* __restrict__ R_w, const float* __restrict__ W_ih,
    const float* __restrict__ W_hh, const float* __restrict__ b_ih,
    const float* __restrict__ b_hh,
    const float* __restrict__ l1_w1, const float* __restrict__ l1_b1,
    const float* __restrict__ l1_w2, const float* __restrict__ l1_b2,
    const float* __restrict__ l2_w1, const float* __restrict__ l2_b1,
    const float* __restrict__ l2_w2, const float* __restrict__ l2_b2,
    float* __restrict__ out_alpha, float* __restrict__ out_h,
    float* __restrict__ out_c3)
{
    __shared__ __align__(16) union { GruLds g; FillLds f; } S;

    const int tid = threadIdx.x;
    const int bid = blockIdx.x;

    if (bid < GRUB) {
        // ===== GRU + mlp1 + alpha: 2 rows/block, 4 role-waves each, 1 barrier/step =====
        const int wid  = tid >> 6;
        const int rw   = wid >> 2;          // row within block (0/1)
        const int role = wid & 3;           // 0=r,1=z,2=n,3=mlp1
        const int j    = tid & 63;
        const int b    = bid * 2 + rw;

        {   // stage gam/r for both rows
            int sec = tid >> 8, t2 = tid & 255;
            if (t2 < Sn) {
                int bb = bid * 2 + sec;
                S.g.gam[sec][t2] = D_w[d_seq[bb * Sn + t2]];
                S.g.r[sec][t2]   = r_seq[bb * Sn + t2];
            }
        }
        // fold xg: u = W_ih[rho,:64]@v_d ; w0/w1 = W_ih[rho,64:]@R_w[r] + b_ih[rho]
        if (tid < 192) {
            const float4* rp  = (const float4*)(W_ih + (size_t)tid * 128);
            const float4* vd4 = (const float4*)v_d;
            const float4* q04 = (const float4*)R_w;
            const float4* q14 = (const float4*)(R_w + 64);
            float u = 0.f, w0 = 0.f, w1 = 0.f;
            #pragma unroll 4
            for (int k = 0; k < 16; ++k) {
                float4 a  = rp[k];
                float4 bb = rp[16 + k];
                float4 vd = vd4[k], q0 = q04[k], q1 = q14[k];
                u  += a.x*vd.x + a.y*vd.y + a.z*vd.z + a.w*vd.w;
                w0 += bb.x*q0.x + bb.y*q0.y + bb.z*q0.z + bb.w*q0.w;
                w1 += bb.x*q1.x + bb.y*q1.y + bb.z*q1.z + bb.w*q1.w;
            }
            float bih = b_ih[tid];
            S.g.u[tid]  = u;
            S.g.w0[tid] = w0 + bih;
            S.g.w1[tid] = w1 + bih;
        }
        // per-wave weight row
        float w[64];
        {
            const float* src = (role < 3) ? (W_hh + (size_t)(role * 64 + j) * 64)
                                          : (l1_w1 + (size_t)j * 64);
            const float4* s4 = (const float4*)src;
            #pragma unroll
            for (int k = 0; k < 16; ++k) {
                float4 v = s4[k];
                w[4*k+0]=v.x; w[4*k+1]=v.y; w[4*k+2]=v.z; w[4*k+3]=v.w;
            }
        }
        float bown = 0.f, l1b = 0.f, l1w2v = 0.f;
        if (role < 3) {
            bown = b_hh[role * 64 + j];
            S.g.hg[rw][0][role * 64 + j] = bown;   // h0=0 -> hg(t=0)=b_hh
        } else {
            l1b = l1_b1[j]; l1w2v = l1_w2[j];
        }
        const float l1b2c = l1_b2[0];
        __syncthreads();

        const float uj  = S.g.u[j],  u1  = S.g.u[64+j],  u2  = S.g.u[128+j];
        const float w00 = S.g.w0[j], w01 = S.g.w0[64+j], w02 = S.g.w0[128+j];
        const float w10 = S.g.w1[j], w11 = S.g.w1[64+j], w12 = S.g.w1[128+j];

        float vh = 0.f;
        float* outh_base = out_h + (size_t)b * Sn * 64;
        const int rloc = 4 * role + (j >> 4);
        const int cloc = (j & 15) * 4;

        for (int t = 0; t < Sn; ++t) {
            if (t && (t & 15) == 0) {          // flush completed ring half
                const int hb = ((t >> 4) & 1) ^ 1;
                float4 v4 = *(const float4*)&S.g.ring[rw][hb][rloc][cloc];
                *(float4*)(outh_base + (size_t)(t - 16 + rloc) * 64 + cloc) = v4;
            }
            const int buf = t & 1;
            float gam = S.g.gam[rw][t];
            int   r   = S.g.r[rw][t];
            float hr = S.g.hg[rw][buf][j], hz = S.g.hg[rw][buf][64+j], hn = S.g.hg[rw][buf][128+j];
            float rg = sigmf(fmaf(gam, uj, r ? w10 : w00) + hr);
            float zg = sigmf(fmaf(gam, u1, r ? w11 : w01) + hz);
            float e2 = __expf(2.f * (fmaf(gam, u2, r ? w12 : w02) + rg * hn));
            float ng = (e2 - 1.f) / (e2 + 1.f);     // tanh
            vh = (1.f - zg) * ng + zg * vh;
            // self-broadcast h via per-wave LDS strip, then b128 broadcast reads
            S.g.hbc[wid][j] = vh;
            float a0=0.f, a1=0.f, a2=0.f, a3=0.f;
            #pragma unroll
            for (int k4 = 0; k4 < 16; ++k4) {
                float4 h4 = *(const float4*)&S.g.hbc[wid][k4 * 4];
                a0 = fmaf(w[4*k4+0], h4.x, a0);
                a1 = fmaf(w[4*k4+1], h4.y, a1);
                a2 = fmaf(w[4*k4+2], h4.z, a2);
                a3 = fmaf(w[4*k4+3], h4.w, a3);
            }
            float dot = (a0 + a1) + (a2 + a3);
            if (role < 3) {
                S.g.hg[rw][buf ^ 1][role * 64 + j] = bown + dot;
            } else {
                float p = fmaxf(dot + l1b, 0.f) * l1w2v;
                p += __shfl_xor(p, 1);
                p += __shfl_xor(p, 2);
                p += __shfl_xor(p, 4);
                p += __shfl_xor(p, 8);
                if ((j & 15) == 0) S.g.pPart[rw][t][j >> 4] = p;
                S.g.ring[rw][(t >> 4) & 1][t & 15][j] = vh;
            }
            __syncthreads();
        }
        if (role < 2) {                        // rows 192..199 from ring[rw][0][0..7]
            float4 v4 = *(const float4*)&S.g.ring[rw][0][rloc][cloc];
            *(float4*)(outh_base + (size_t)(192 + rloc) * 64 + cloc) = v4;
        }
        // deferred alpha chain: parallel an-preload + readlane-driven serial walk
        if (role == 3) {
            float4 pp0 = *(const float4*)&S.g.pPart[rw][j][0];
            float4 pp1 = *(const float4*)&S.g.pPart[rw][64 + j][0];
            float4 pp2 = *(const float4*)&S.g.pPart[rw][128 + j][0];
            const int j3 = (j < 8) ? (192 + j) : 199;
            float4 pp3 = *(const float4*)&S.g.pPart[rw][j3][0];
            float an0 = ((pp0.x+pp0.y)+(pp0.z+pp0.w)) + l1b2c;
            float an1 = ((pp1.x+pp1.y)+(pp1.z+pp1.w)) + l1b2c;
            float an2 = ((pp2.x+pp2.y)+(pp2.z+pp2.w)) + l1b2c;
            float an3 = ((pp3.x+pp3.y)+(pp3.z+pp3.w)) + l1b2c;
            float g0 = S.g.gam[rw][j],      g1 = S.g.gam[rw][64 + j];
            float g2 = S.g.gam[rw][128 + j],g3 = S.g.gam[rw][j3];
            int   r0 = S.g.r[rw][j],        r1 = S.g.r[rw][64 + j];
            int   r2 = S.g.r[rw][128 + j],  r3 = S.g.r[rw][j3];
            float alpha = 0.f;
            float* oa = out_alpha + b * Sn;
            for (int t = 0; t < Sn; ++t) {
                const int q = t >> 6, l = t & 63;
                float an, g; int rr;
                if (q == 0)      { an = rlanef(an0,l); g = rlanef(g0,l); rr = __builtin_amdgcn_readlane(r0,l); }
                else if (q == 1) { an = rlanef(an1,l); g = rlanef(g1,l); rr = __builtin_amdgcn_readlane(r1,l); }
                else if (q == 2) { an = rlanef(an2,l); g = rlanef(g2,l); rr = __builtin_amdgcn_readlane(r2,l); }
                else             { an = rlanef(an3,l); g = rlanef(g3,l); rr = __builtin_amdgcn_readlane(r3,l); }
                bool cond = (alpha - g) >= 0.f;
                alpha = rr ? (cond ? an : alpha) : (cond ? alpha : an);
                if (j == 0) oa[t] = alpha;
            }
        }
    } else {
        // ===== C3 chain + full-row streaming fill: one (row, t-half) =====
        const int fb   = bid - GRUB;
        const int b    = fb >> 1;
        const int half = fb & 1;
        if (tid < Sn) {
            S.f.gam[tid] = D_w[d_seq[b*Sn + tid]];
            S.f.r[tid]   = r_seq[b*Sn + tid];
            S.f.c3[tid]  = c3_seq[b*Sn + tid];
        }
        if (tid < 64) {
            const float4* row4 = (const float4*)(l2_w1 + (size_t)tid * 192);
            const float4* vc4  = (const float4*)v_c3;
            const float4* vd4  = (const float4*)v_d;
            const float4* q04  = (const float4*)R_w;
            const float4* q14  = (const float4*)(R_w + 64);
            float a2=0.f, b2=0.f, c0=0.f, c1=0.f;
            #pragma unroll 4
            for (int k = 0; k < 16; ++k) {
                float4 ra = row4[k], rb = row4[16+k], rc = row4[32+k];
                float4 vc = vc4[k], vd = vd4[k], q0 = q04[k], q1 = q14[k];
                a2 += ra.x*vc.x + ra.y*vc.y + ra.z*vc.z + ra.w*vc.w;
                b2 += rb.x*vd.x + rb.y*vd.y + rb.z*vd.z + rb.w*vd.w;
                c0 += rc.x*q0.x + rc.y*q0.y + rc.z*q0.z + rc.w*q0.w;
                c1 += rc.x*q1.x + rc.y*q1.y + rc.z*q1.z + rc.w*q1.w;
            }
            S.f.A[tid]  = a2;
            S.f.Bv[tid] = b2;
            S.f.C0[tid] = c0 + l2_b1[tid];
            S.f.C1[tid] = c1 + l2_b1[tid];
            S.f.W2[tid] = l2_w2[tid];
        }
        if (tid == 0) S.f.l2b2 = l2_b2[0];
        __syncthreads();
        if (tid < Sn) {
            int c = S.f.c3[tid];
            int s = -1;
            for (int u = tid + 1; u < Sn; ++u)
                if (S.f.c3[u] == c) { s = u; break; }
            S.f.succ[tid] = s;
            int rt = 1;
            for (int u = 0; u < tid; ++u)
                if (S.f.c3[u] == c) { rt = 0; break; }
            S.f.root[tid] = rt;
        }
        __syncthreads();
        if (tid < 256) {   // chain walk, 16-lane groups
            const int g  = tid >> 4;
            const int l  = tid & 15;
            const int j0 = l * 4;
            float A0=S.f.A[j0],  A1=S.f.A[j0+1],  A2=S.f.A[j0+2],  A3=S.f.A[j0+3];
            float B0=S.f.Bv[j0], B1=S.f.Bv[j0+1], B2=S.f.Bv[j0+2], B3=S.f.Bv[j0+3];
            float C00=S.f.C0[j0],C01=S.f.C0[j0+1],C02=S.f.C0[j0+2],C03=S.f.C0[j0+3];
            float C10=S.f.C1[j0],C11=S.f.C1[j0+1],C12=S.f.C1[j0+2],C13=S.f.C1[j0+3];
            float W0=S.f.W2[j0], W1=S.f.W2[j0+1], W2v=S.f.W2[j0+2],W3=S.f.W2[j0+3];
            float l2b2 = S.f.l2b2;
            for (int t0 = g; t0 < Sn; t0 += 16) {
                if (!S.f.root[t0]) continue;
                float beta = 0.f;
                int t = t0;
                while (t >= 0) {
                    float gam = S.f.gam[t];
                    int   r   = S.f.r[t];
                    float s = W0*fmaxf(A0*beta + B0*gam + (r ? C10 : C00), 0.f)
                            + W1*fmaxf(A1*beta + B1*gam + (r ? C11 : C01), 0.f)
                            + W2v*fmaxf(A2*beta + B2*gam + (r ? C12 : C02), 0.f)
                            + W3*fmaxf(A3*beta + B3*gam + (r ? C13 : C03), 0.f);
                    s += __shfl_xor(s, 1, 16);
                    s += __shfl_xor(s, 2, 16);
                    s += __shfl_xor(s, 4, 16);
                    s += __shfl_xor(s, 8, 16);
                    beta = s + l2b2;
                    if (l == 0) S.f.val[t] = beta;
                    t = S.f.succ[t];
                }
            }
        }
        __syncthreads();
        // fill: thread owns 2 f4 columns; whole 16KB row stored contiguously per t
        if (tid < 500) {
            const int cA = tid * 4, cB = 2000 + tid * 4;
            float4 qA = make_float4(0.f,0.f,0.f,0.f), qB = qA;
            const int t0 = half * 100;
            for (int t = 0; t < t0; ++t) {      // pre-scan (no stores)
                int cc = S.f.c3[t]; float v = S.f.val[t];
                UPD(qA, cA) UPD(qB, cB)
            }
            float* rowp = out_c3 + (size_t)b * Sn * NC3n + (size_t)t0 * NC3n;
            for (int t = t0; t < t0 + 100; ++t) {
                int cc = S.f.c3[t]; float v = S.f.val[t];
                UPD(qA, cA) UPD(qB, cB)
                *(float4*)(rowp + cA) = qA;
                *(float4*)(rowp + cB) = qB;
                rowp += NC3n;
            }
        }
    }
}

extern "C" void kernel_launch(void* const* d_in, const int* in_sizes, int n_in,
                              void* d_out, int out_size, void* d_ws, size_t ws_size,
                              hipStream_t stream)
{
    const int*   c3_seq = (const int*)  d_in[0];
    const int*   d_seq  = (const int*)  d_in[1];
    const int*   r_seq  = (const int*)  d_in[2];
    const float* v_c3   = (const float*)d_in[3];
    const float* D_w    = (const float*)d_in[4];
    const float* v_d    = (const float*)d_in[5];
    const float* R_w    = (const float*)d_in[6];
    const float* W_ih   = (const float*)d_in[7];
    const float* W_hh   = (const float*)d_in[8];
    const float* b_ih   = (const float*)d_in[9];
    const float* b_hh   = (const float*)d_in[10];
    const float* l1_w1  = (const float*)d_in[11];
    const float* l1_b1  = (const float*)d_in[12];
    const float* l1_w2  = (const float*)d_in[13];
    const float* l1_b2  = (const float*)d_in[14];
    const float* l2_w1  = (const float*)d_in[15];
    const float* l2_b1  = (const float*)d_in[16];
    const float* l2_w2  = (const float*)d_in[17];
    const float* l2_b2  = (const float*)d_in[18];

    float* out_alpha = (float*)d_out;
    float* out_h     = out_alpha + Bn*Sn;
    float* out_c3    = out_h + (size_t)Bn*Sn*64;

    fused3_kernel<<<GRUB + FILLB, 512, 0, stream>>>(
        c3_seq, d_seq, r_seq, v_c3, D_w, v_d, R_w, W_ih, W_hh, b_ih, b_hh,
        l1_w1, l1_b1, l1_w2, l1_b2, l2_w1, l2_b1, l2_w2, l2_b2,
        out_alpha, out_h, out_c3);
}

// Round 11
// 161.209 us; speedup vs baseline: 3.4249x; 1.2765x over previous
//
#include <hip/hip_runtime.h>
#include <math.h>

#define Bn 128
#define Sn 200
#define NC3n 4000
#define GRUB Bn                 // 128 GRU blocks, 1 row each
#define FILLB (Bn * 4)          // 512 fill blocks, (b, quarter)

__device__ __forceinline__ float fexp(float x) { return __builtin_amdgcn_exp2f(x * 1.44269504f); }
__device__ __forceinline__ float frcp(float x) { return __builtin_amdgcn_rcpf(x); }
__device__ __forceinline__ float fsig(float x) { return frcp(1.f + fexp(-x)); }
__device__ __forceinline__ float rlanef(float v, int k) {
    return __int_as_float(__builtin_amdgcn_readlane(__float_as_int(v), k));
}

#define UPD(q, cbase) { int d = cc - (cbase); if ((unsigned)d < 4u) { \
    q.x = (d==0)?v:q.x; q.y = (d==1)?v:q.y; q.z = (d==2)?v:q.z; q.w = (d==3)?v:q.w; } }

struct GruLds {                 // ~17.5 KB
    float ring[2][16][64];      // out_h staging (8 KB)
    float pPart[Sn][4];         // mlp1 16-lane partials
    float hbc[4][64];           // per-wave h broadcast strips
    float u[192], w0[192], w1[192];
    float hg[2][192];           // ping-pong W_hh@h + b_hh
    float gam[Sn];
    int   r[Sn];
};
struct FillLds {                // ~6.2 KB
    float gam[Sn], val[Sn];
    int   r[Sn], c3[Sn], succ[Sn], root[Sn];
    float A[64], Bv[64], C0[64], C1[64], W2[64];
    float l2b2;
};

__global__ __launch_bounds__(256, 2) void fused4_kernel(
    const int* __restrict__ c3_seq, const int* __restrict__ d_seq,
    const int* __restrict__ r_seq, const float* __restrict__ v_c3,
    const float* __restrict__ D_w, const float* __restrict__ v_d,
    const float* __restrict__ R_w, const float* __restrict__ W_ih,
    const float* __restrict__ W_hh, const float* __restrict__ b_ih,
    const float* __restrict__ b_hh,
    const float* __restrict__ l1_w1, const float* __restrict__ l1_b1,
    const float* __restrict__ l1_w2, const float* __restrict__ l1_b2,
    const float* __restrict__ l2_w1, const float* __restrict__ l2_b1,
    const float* __restrict__ l2_w2, const float* __restrict__ l2_b2,
    float* __restrict__ out_alpha, float* __restrict__ out_h,
    float* __restrict__ out_c3)
{
    __shared__ __align__(16) union { GruLds g; FillLds f; } S;

    const int tid = threadIdx.x;
    const int bid = blockIdx.x;

    if (bid < GRUB) {
        // ===== GRU + mlp1 + alpha: 1 row, 4 role waves, 1 barrier/step =====
        __builtin_amdgcn_s_setprio(1);
        const int b    = bid;
        const int role = tid >> 6;          // 0=r,1=z,2=n,3=mlp1
        const int j    = tid & 63;

        if (tid < Sn) {
            S.g.gam[tid] = D_w[d_seq[b * Sn + tid]];
            S.g.r[tid]   = r_seq[b * Sn + tid];
        }
        // fold xg: u = W_ih[rho,:64]@v_d ; w0/w1 = W_ih[rho,64:]@R_w[r] + b_ih[rho]
        if (tid < 192) {
            const float4* rp  = (const float4*)(W_ih + (size_t)tid * 128);
            const float4* vd4 = (const float4*)v_d;
            const float4* q04 = (const float4*)R_w;
            const float4* q14 = (const float4*)(R_w + 64);
            float u = 0.f, w0 = 0.f, w1 = 0.f;
            #pragma unroll 4
            for (int k = 0; k < 16; ++k) {
                float4 a  = rp[k];
                float4 bb = rp[16 + k];
                float4 vd = vd4[k], q0 = q04[k], q1 = q14[k];
                u  += a.x*vd.x + a.y*vd.y + a.z*vd.z + a.w*vd.w;
                w0 += bb.x*q0.x + bb.y*q0.y + bb.z*q0.z + bb.w*q0.w;
                w1 += bb.x*q1.x + bb.y*q1.y + bb.z*q1.z + bb.w*q1.w;
            }
            float bih = b_ih[tid];
            S.g.u[tid]  = u;
            S.g.w0[tid] = w0 + bih;
            S.g.w1[tid] = w1 + bih;
        }
        // per-wave weight row: role<3 -> W_hh row role*64+j ; role==3 -> l1_w1 row j
        float w[64];
        {
            const float* src = (role < 3) ? (W_hh + (size_t)(role * 64 + j) * 64)
                                          : (l1_w1 + (size_t)j * 64);
            const float4* s4 = (const float4*)src;
            #pragma unroll
            for (int k = 0; k < 16; ++k) {
                float4 v = s4[k];
                w[4*k+0]=v.x; w[4*k+1]=v.y; w[4*k+2]=v.z; w[4*k+3]=v.w;
            }
        }
        float bown = 0.f, l1b = 0.f, l1w2v = 0.f;
        if (role < 3) {
            bown = b_hh[role * 64 + j];
            S.g.hg[0][role * 64 + j] = bown;    // h0=0 -> hg(t=0)=b_hh
        } else {
            l1b = l1_b1[j]; l1w2v = l1_w2[j];
        }
        const float l1b2c = l1_b2[0];
        __syncthreads();

        const float uj  = S.g.u[j],  u1  = S.g.u[64+j],  u2  = S.g.u[128+j];
        const float w00 = S.g.w0[j], w01 = S.g.w0[64+j], w02 = S.g.w0[128+j];
        const float w10 = S.g.w1[j], w11 = S.g.w1[64+j], w12 = S.g.w1[128+j];

        float vh = 0.f;
        float* outh_base = out_h + (size_t)b * Sn * 64;
        const int rloc = 4 * role + (j >> 4);
        const int cloc = (j & 15) * 4;

        for (int t = 0; t < Sn; ++t) {
            if (t && (t & 15) == 0) {           // flush completed ring half
                const int hb = ((t >> 4) & 1) ^ 1;
                float4 v4 = *(const float4*)&S.g.ring[hb][rloc][cloc];
                *(float4*)(outh_base + (size_t)(t - 16 + rloc) * 64 + cloc) = v4;
            }
            const int buf = t & 1;
            float gam = S.g.gam[t];
            int   r   = S.g.r[t];
            float hr = S.g.hg[buf][j], hz = S.g.hg[buf][64+j], hn = S.g.hg[buf][128+j];
            // gates (redundant in all 4 waves), fast rcp/exp2 — no IEEE div chains
            float rg = fsig(fmaf(gam, uj, r ? w10 : w00) + hr);
            float zg = fsig(fmaf(gam, u1, r ? w11 : w01) + hz);
            float e2 = fexp(2.f * (fmaf(gam, u2, r ? w12 : w02) + rg * hn));
            float ng = 1.f - 2.f * frcp(e2 + 1.f);   // tanh
            vh = (1.f - zg) * ng + zg * vh;
            // self-broadcast h: write strip, then BATCH all 16 b128 reads (one wait)
            S.g.hbc[role][j] = vh;
            float4 hreg[16];
            #pragma unroll
            for (int k = 0; k < 16; ++k)
                hreg[k] = *(const float4*)&S.g.hbc[role][k * 4];
            __builtin_amdgcn_sched_barrier(0);  // keep loads batched above the fmas
            float a0=0.f, a1=0.f, a2=0.f, a3=0.f;
            #pragma unroll
            for (int k = 0; k < 16; ++k) {
                a0 = fmaf(w[4*k+0], hreg[k].x, a0);
                a1 = fmaf(w[4*k+1], hreg[k].y, a1);
                a2 = fmaf(w[4*k+2], hreg[k].z, a2);
                a3 = fmaf(w[4*k+3], hreg[k].w, a3);
            }
            float dot = (a0 + a1) + (a2 + a3);
            if (role < 3) {
                S.g.hg[buf ^ 1][role * 64 + j] = bown + dot;
            } else {
                float p = fmaxf(dot + l1b, 0.f) * l1w2v;
                p += __shfl_xor(p, 1);
                p += __shfl_xor(p, 2);
                p += __shfl_xor(p, 4);
                p += __shfl_xor(p, 8);
                if ((j & 15) == 0) S.g.pPart[t][j >> 4] = p;
                S.g.ring[(t >> 4) & 1][t & 15][j] = vh;
            }
            __syncthreads();
        }
        if (role < 2) {                         // rows 192..199 from ring[0][0..7]
            float4 v4 = *(const float4*)&S.g.ring[0][rloc][cloc];
            *(float4*)(outh_base + (size_t)(192 + rloc) * 64 + cloc) = v4;
        }
        // deferred alpha chain: parallel an-preload + readlane-driven serial walk
        if (role == 3) {
            float4 pp0 = *(const float4*)&S.g.pPart[j][0];
            float4 pp1 = *(const float4*)&S.g.pPart[64 + j][0];
            float4 pp2 = *(const float4*)&S.g.pPart[128 + j][0];
            const int j3 = (j < 8) ? (192 + j) : 199;
            float4 pp3 = *(const float4*)&S.g.pPart[j3][0];
            float an0 = ((pp0.x+pp0.y)+(pp0.z+pp0.w)) + l1b2c;
            float an1 = ((pp1.x+pp1.y)+(pp1.z+pp1.w)) + l1b2c;
            float an2 = ((pp2.x+pp2.y)+(pp2.z+pp2.w)) + l1b2c;
            float an3 = ((pp3.x+pp3.y)+(pp3.z+pp3.w)) + l1b2c;
            float g0 = S.g.gam[j],       g1 = S.g.gam[64 + j];
            float g2 = S.g.gam[128 + j], g3 = S.g.gam[j3];
            int   r0 = S.g.r[j],         r1 = S.g.r[64 + j];
            int   r2 = S.g.r[128 + j],   r3 = S.g.r[j3];
            float alpha = 0.f;
            float* oa = out_alpha + b * Sn;
            for (int t = 0; t < Sn; ++t) {
                const int q = t >> 6, l = t & 63;
                float an, g; int rr;
                if (q == 0)      { an = rlanef(an0,l); g = rlanef(g0,l); rr = __builtin_amdgcn_readlane(r0,l); }
                else if (q == 1) { an = rlanef(an1,l); g = rlanef(g1,l); rr = __builtin_amdgcn_readlane(r1,l); }
                else if (q == 2) { an = rlanef(an2,l); g = rlanef(g2,l); rr = __builtin_amdgcn_readlane(r2,l); }
                else             { an = rlanef(an3,l); g = rlanef(g3,l); rr = __builtin_amdgcn_readlane(r3,l); }
                bool cond = (alpha - g) >= 0.f;
                alpha = rr ? (cond ? an : alpha) : (cond ? alpha : an);
                if (j == 0) oa[t] = alpha;
            }
        }
    } else {
        // ===== C3 chain + contiguous forward-fill: one (row, quarter) =====
        const int fb = bid - GRUB;
        const int b  = fb >> 2;
        const int qt = fb & 3;
        if (tid < Sn) {
            S.f.gam[tid] = D_w[d_seq[b*Sn + tid]];
            S.f.r[tid]   = r_seq[b*Sn + tid];
            S.f.c3[tid]  = c3_seq[b*Sn + tid];
        }
        if (tid < 64) {
            const float4* row4 = (const float4*)(l2_w1 + (size_t)tid * 192);
            const float4* vc4  = (const float4*)v_c3;
            const float4* vd4  = (const float4*)v_d;
            const float4* q04  = (const float4*)R_w;
            const float4* q14  = (const float4*)(R_w + 64);
            float a2=0.f, b2=0.f, c0=0.f, c1=0.f;
            #pragma unroll 4
            for (int k = 0; k < 16; ++k) {
                float4 ra = row4[k], rb = row4[16+k], rc = row4[32+k];
                float4 vc = vc4[k], vd = vd4[k], q0 = q04[k], q1 = q14[k];
                a2 += ra.x*vc.x + ra.y*vc.y + ra.z*vc.z + ra.w*vc.w;
                b2 += rb.x*vd.x + rb.y*vd.y + rb.z*vd.z + rb.w*vd.w;
                c0 += rc.x*q0.x + rc.y*q0.y + rc.z*q0.z + rc.w*q0.w;
                c1 += rc.x*q1.x + rc.y*q1.y + rc.z*q1.z + rc.w*q1.w;
            }
            S.f.A[tid]  = a2;
            S.f.Bv[tid] = b2;
            S.f.C0[tid] = c0 + l2_b1[tid];
            S.f.C1[tid] = c1 + l2_b1[tid];
            S.f.W2[tid] = l2_w2[tid];
        }
        if (tid == 0) S.f.l2b2 = l2_b2[0];
        __syncthreads();
        if (tid < Sn) {
            int c = S.f.c3[tid];
            int s = -1;
            for (int u = tid + 1; u < Sn; ++u)
                if (S.f.c3[u] == c) { s = u; break; }
            S.f.succ[tid] = s;
            int rt = 1;
            for (int u = 0; u < tid; ++u)
                if (S.f.c3[u] == c) { rt = 0; break; }
            S.f.root[tid] = rt;
        }
        __syncthreads();
        {   // chain walk, 16-lane groups
            const int g  = tid >> 4;
            const int l  = tid & 15;
            const int j0 = l * 4;
            float A0=S.f.A[j0],  A1=S.f.A[j0+1],  A2=S.f.A[j0+2],  A3=S.f.A[j0+3];
            float B0=S.f.Bv[j0], B1=S.f.Bv[j0+1], B2=S.f.Bv[j0+2], B3=S.f.Bv[j0+3];
            float C00=S.f.C0[j0],C01=S.f.C0[j0+1],C02=S.f.C0[j0+2],C03=S.f.C0[j0+3];
            float C10=S.f.C1[j0],C11=S.f.C1[j0+1],C12=S.f.C1[j0+2],C13=S.f.C1[j0+3];
            float W0=S.f.W2[j0], W1=S.f.W2[j0+1], W2v=S.f.W2[j0+2],W3=S.f.W2[j0+3];
            float l2b2 = S.f.l2b2;
            for (int t0 = g; t0 < Sn; t0 += 16) {
                if (!S.f.root[t0]) continue;
                float beta = 0.f;
                int t = t0;
                while (t >= 0) {
                    float gam = S.f.gam[t];
                    int   r   = S.f.r[t];
                    float s = W0*fmaxf(A0*beta + B0*gam + (r ? C10 : C00), 0.f)
                            + W1*fmaxf(A1*beta + B1*gam + (r ? C11 : C01), 0.f)
                            + W2v*fmaxf(A2*beta + B2*gam + (r ? C12 : C02), 0.f)
                            + W3*fmaxf(A3*beta + B3*gam + (r ? C13 : C03), 0.f);
                    s += __shfl_xor(s, 1, 16);
                    s += __shfl_xor(s, 2, 16);
                    s += __shfl_xor(s, 4, 16);
                    s += __shfl_xor(s, 8, 16);
                    beta = s + l2b2;
                    if (l == 0) S.f.val[t] = beta;
                    t = S.f.succ[t];
                }
            }
        }
        __syncthreads();
        // forward-fill 50 rows x 16KB, contiguous per-block stream
        const int cA = tid*4, cB = 1024 + tid*4, cC = 2048 + tid*4, cD = 3072 + tid*4;
        float4 qA = make_float4(0.f,0.f,0.f,0.f), qB = qA, qC = qA, qD = qA;
        const int t0 = qt * 50;
        for (int t = 0; t < t0; ++t) {          // pre-scan (no stores)
            int cc = S.f.c3[t]; float v = S.f.val[t];
            UPD(qA, cA) UPD(qB, cB) UPD(qC, cC) UPD(qD, cD)
        }
        float* rowp = out_c3 + (size_t)b * Sn * NC3n + (size_t)t0 * NC3n;
        const bool doD = (tid < 232);
        for (int t = t0; t < t0 + 50; ++t) {
            int cc = S.f.c3[t]; float v = S.f.val[t];
            UPD(qA, cA) UPD(qB, cB) UPD(qC, cC) UPD(qD, cD)
            *(float4*)(rowp + cA) = qA;
            *(float4*)(rowp + cB) = qB;
            *(float4*)(rowp + cC) = qC;
            if (doD) *(float4*)(rowp + cD) = qD;
            rowp += NC3n;
        }
    }
}

extern "C" void kernel_launch(void* const* d_in, const int* in_sizes, int n_in,
                              void* d_out, int out_size, void* d_ws, size_t ws_size,
                              hipStream_t stream)
{
    const int*   c3_seq = (const int*)  d_in[0];
    const int*   d_seq  = (const int*)  d_in[1];
    const int*   r_seq  = (const int*)  d_in[2];
    const float* v_c3   = (const float*)d_in[3];
    const float* D_w    = (const float*)d_in[4];
    const float* v_d    = (const float*)d_in[5];
    const float* R_w    = (const float*)d_in[6];
    const float* W_ih   = (const float*)d_in[7];
    const float* W_hh   = (const float*)d_in[8];
    const float* b_ih   = (const float*)d_in[9];
    const float* b_hh   = (const float*)d_in[10];
    const float* l1_w1  = (const float*)d_in[11];
    const float* l1_b1  = (const float*)d_in[12];
    const float* l1_w2  = (const float*)d_in[13];
    const float* l1_b2  = (const float*)d_in[14];
    const float* l2_w1  = (const float*)d_in[15];
    const float* l2_b1  = (const float*)d_in[16];
    const float* l2_w2  = (const float*)d_in[17];
    const float* l2_b2  = (const float*)d_in[18];

    float* out_alpha = (float*)d_out;
    float* out_h     = out_alpha + Bn*Sn;
    float* out_c3    = out_h + (size_t)Bn*Sn*64;

    fused4_kernel<<<GRUB + FILLB, 256, 0, stream>>>(
        c3_seq, d_seq, r_seq, v_c3, D_w, v_d, R_w, W_ih, W_hh, b_ih, b_hh,
        l1_w1, l1_b1, l1_w2, l1_b2, l2_w1, l2_b1, l2_w2, l2_b2,
        out_alpha, out_h, out_c3);
}